// Round 15
// baseline (999.476 us; speedup 1.0000x reference)
//
#include <hip/hip_runtime.h>
#include <math.h>

#define NN 50000
#define NE 800000
#define EAUG (NE + NN)
#define HD 128
#define NC 40
#define BN_EPS 1e-5f
#define LDA 136  // padded LDS stride (elems): 272B/row -> 2-way bank aliasing (free)

typedef short bf16x8 __attribute__((ext_vector_type(8)));
typedef float f32x4 __attribute__((ext_vector_type(4)));

// ---------------------------------------------------------------- utilities
static __device__ __forceinline__ float softplusf(float z) {
    if (z > 20.f) return z;
    if (z < -20.f) return expf(z);
    return log1pf(expf(z));
}

static __device__ __forceinline__ unsigned short f2bf(float f) {
    union { float f; unsigned int u; } v;
    v.f = f;
    unsigned int u = v.u;
    unsigned int r = (u + 0x7fffu + ((u >> 16) & 1u)) >> 16;
    return (unsigned short)r;
}
static __device__ __forceinline__ float b2f_lo(unsigned int u) {
    union { unsigned int i; float f; } v; v.i = u << 16; return v.f;
}
static __device__ __forceinline__ float b2f_hi(unsigned int u) {
    union { unsigned int i; float f; } v; v.i = u & 0xffff0000u; return v.f;
}

// ---------------------------------------------------------------- CSR build
__global__ __launch_bounds__(256) void hist_kernel(const int* __restrict__ ei,
                                                   int* __restrict__ cnt) {
    int e = blockIdx.x * 256 + threadIdx.x;
    if (e >= EAUG) return;
    int c = (e < NE) ? ei[NE + e] : (e - NE);
    atomicAdd(&cnt[c], 1);
}

__global__ __launch_bounds__(1024) void scan_kernel(const int* __restrict__ cnt,
                                                    int* __restrict__ off,
                                                    int* __restrict__ wp) {
    __shared__ int sdata[1024];
    __shared__ int carry;
    int tid = threadIdx.x;
    if (tid == 0) carry = 0;
    __syncthreads();
    for (int base = 0; base < NN; base += 1024) {
        int i = base + tid;
        int v = (i < NN) ? cnt[i] : 0;
        sdata[tid] = v;
        __syncthreads();
        for (int ofs = 1; ofs < 1024; ofs <<= 1) {
            int t = (tid >= ofs) ? sdata[tid - ofs] : 0;
            __syncthreads();
            sdata[tid] += t;
            __syncthreads();
        }
        int excl = sdata[tid] - v + carry;
        if (i < NN) { off[i] = excl; wp[i] = excl; }
        __syncthreads();
        if (tid == 1023) carry += sdata[1023];
        __syncthreads();
    }
    if (tid == 0) off[NN] = carry;   // == EAUG
}

// stores (src,dst) per CSR slot; no edge-id indirection needed downstream
__global__ __launch_bounds__(256) void scatter_kernel(const int* __restrict__ ei,
                                                      int* __restrict__ wp,
                                                      int* __restrict__ csr_s,
                                                      int* __restrict__ csr_c) {
    int e = blockIdx.x * 256 + threadIdx.x;
    if (e >= EAUG) return;
    int r, c;
    if (e < NE) { r = ei[e]; c = ei[NE + e]; } else { r = c = e - NE; }
    int pos = atomicAdd(&wp[c], 1);
    csr_s[pos] = r;
    csr_c[pos] = c;
}

// ---------------------------------------------------------------- MFMA GEMM: O_m = A @ W_m^T (+bias)
// BFMASK bit m: output m stored as bf16 (ushort), else fp32.
template <int NM, int BFMASK>
__global__ __launch_bounds__(256) void gemm_mfma(
    const float* __restrict__ A, int nrows,
    const float* __restrict__ W0, const float* __restrict__ B0, void* __restrict__ O0,
    const float* __restrict__ W1, const float* __restrict__ B1, void* __restrict__ O1,
    const float* __restrict__ W2, const float* __restrict__ B2, void* __restrict__ O2,
    const float* __restrict__ W3, const float* __restrict__ B3, void* __restrict__ O3) {
    __shared__ __align__(16) unsigned short As[64 * LDA];
    __shared__ __align__(16) unsigned short Bs_lds[128 * LDA];
    const int t = threadIdx.x;
    const int r0 = blockIdx.x * 64;

    {   // stage A tile (fp32 -> bf16)
        const float4* A4 = (const float4*)A;
#pragma unroll
        for (int i = 0; i < 8; i++) {
            int f4 = t + i * 256;
            int row = f4 >> 5, q = f4 & 31;
            float4 v = make_float4(0.f, 0.f, 0.f, 0.f);
            if (r0 + row < nrows) v = A4[(size_t)(r0 + row) * 32 + q];
            ushort4 b;
            b.x = f2bf(v.x); b.y = f2bf(v.y); b.z = f2bf(v.z); b.w = f2bf(v.w);
            *(ushort4*)&As[row * LDA + q * 4] = b;
        }
    }

    const float* Ws[4] = {W0, W1, W2, W3};
    const float* Bb[4] = {B0, B1, B2, B3};
    void* Os[4] = {O0, O1, O2, O3};
    const int wv = t >> 6;
    const int ln = t & 63;
    const int lrow = ln & 15;
    const int lk = ln >> 4;

#pragma unroll
    for (int m = 0; m < NM; m++) {
        __syncthreads();
        {
            const float4* Wm4 = (const float4*)Ws[m];
#pragma unroll
            for (int i = 0; i < 16; i++) {
                int f4 = t + i * 256;
                int c = f4 >> 5, q = f4 & 31;
                float4 v = Wm4[f4];
                ushort4 b;
                b.x = f2bf(v.x); b.y = f2bf(v.y); b.z = f2bf(v.z); b.w = f2bf(v.w);
                *(ushort4*)&Bs_lds[c * LDA + q * 4] = b;
            }
        }
        __syncthreads();

        f32x4 acc[8];
#pragma unroll
        for (int nt = 0; nt < 8; nt++) acc[nt] = (f32x4){0.f, 0.f, 0.f, 0.f};

#pragma unroll
        for (int ks = 0; ks < 4; ks++) {
            int kb = ks * 32 + lk * 8;
            bf16x8 af = *(const bf16x8*)&As[(wv * 16 + lrow) * LDA + kb];
#pragma unroll
            for (int nt = 0; nt < 8; nt++) {
                bf16x8 bfr = *(const bf16x8*)&Bs_lds[(nt * 16 + lrow) * LDA + kb];
                acc[nt] = __builtin_amdgcn_mfma_f32_16x16x32_bf16(af, bfr, acc[nt], 0, 0, 0);
            }
        }

        const float* bias = Bb[m];
#pragma unroll
        for (int nt = 0; nt < 8; nt++) {
            int col = nt * 16 + lrow;
            float bv = bias ? bias[col] : 0.f;
#pragma unroll
            for (int j = 0; j < 4; j++) {
                int row = r0 + wv * 16 + lk * 4 + j;
                if (row < nrows) {
                    float val = acc[nt][j] + bv;
                    if ((BFMASK >> m) & 1)
                        ((unsigned short*)Os[m])[(size_t)row * HD + col] = f2bf(val);
                    else
                        ((float*)Os[m])[(size_t)row * HD + col] = val;
                }
            }
        }
    }
}

// ---------------------------------------------------------------- batchnorm
__global__ __launch_bounds__(256) void bn_reduce(const float* __restrict__ X,
                                                 float* __restrict__ sums) {
    int f = threadIdx.x & 127;
    int half = threadIdx.x >> 7;
    float s1 = 0.f, s2 = 0.f;
    for (int r = blockIdx.x * 2 + half; r < NN; r += gridDim.x * 2) {
        float v = X[(size_t)r * HD + f];
        s1 += v;
        s2 += v * v;
    }
    __shared__ float sm[512];
    sm[threadIdx.x] = s1;
    sm[256 + threadIdx.x] = s2;
    __syncthreads();
    if (half == 0) {
        atomicAdd(&sums[f], sm[f] + sm[128 + f]);
        atomicAdd(&sums[128 + f], sm[256 + f] + sm[256 + 128 + f]);
    }
}

__global__ __launch_bounds__(256) void bn_apply(const float* __restrict__ in,
                                                const float* __restrict__ sums,
                                                const float* __restrict__ gamma,
                                                const float* __restrict__ beta,
                                                const float* __restrict__ resid,
                                                float* __restrict__ out) {
    int idx = blockIdx.x * 256 + threadIdx.x;
    int f4 = idx & 31;
    float4 s1 = ((const float4*)sums)[f4];
    float4 s2 = ((const float4*)sums)[32 + f4];
    float4 g = ((const float4*)gamma)[f4];
    float4 bt = ((const float4*)beta)[f4];
    float4 v = ((const float4*)in)[idx];
    const float invn = 1.f / (float)NN;
    float4 o;
#define BN1(comp)                                                          \
    {                                                                      \
        float mean = s1.comp * invn;                                       \
        float var = s2.comp * invn - mean * mean;                          \
        float y = g.comp * (v.comp - mean) * rsqrtf(var + BN_EPS) + bt.comp; \
        o.comp = fmaxf(y, 0.f);                                            \
    }
    BN1(x) BN1(y) BN1(z) BN1(w)
#undef BN1
    if (resid) {
        float4 rv = ((const float4*)resid)[idx];
        o.x += rv.x; o.y += rv.y; o.z += rv.z; o.w += rv.w;
    }
    ((float4*)out)[idx] = o;
}

// ---------------------------------------------------------------- per-node dots from bf16 xg
__global__ __launch_bounds__(256) void node_dots(const unsigned short* __restrict__ xgb,
                                                 const float* __restrict__ Wh,
                                                 float* __restrict__ ar,
                                                 float* __restrict__ ac) {
    int wid = (blockIdx.x * 256 + threadIdx.x) >> 6;
    int l = threadIdx.x & 63;
    if (wid >= NN) return;
    unsigned int u = ((const unsigned int*)(xgb + (size_t)wid * HD))[l];
    float fx = b2f_lo(u), fy = b2f_hi(u);
    float2 wa = ((const float2*)Wh)[l];
    float2 wb = ((const float2*)Wh)[64 + l];
    float pa = fx * wa.x + fy * wa.y;
    float pb = fx * wb.x + fy * wb.y;
#pragma unroll
    for (int ofs = 1; ofs < 64; ofs <<= 1) {
        pa += __shfl_xor(pa, ofs);
        pb += __shfl_xor(pb, ofs);
    }
    if (l == 0) { ar[wid] = pa; ac[wid] = pb; }
}

// ---------------------------------------------------------------- edge pass (CSR order): s_ij -> exp terms + z sums
__global__ __launch_bounds__(256) void edge_pass(const unsigned short* __restrict__ xgb,
                                                 const float* __restrict__ ar,
                                                 const float* __restrict__ ac,
                                                 const int* __restrict__ csr_s,
                                                 const int* __restrict__ csr_c,
                                                 const float* __restrict__ bh,
                                                 float* __restrict__ econ,
                                                 float* __restrict__ edis,
                                                 float* __restrict__ zcon,
                                                 float* __restrict__ zdis) {
    int gid = blockIdx.x * 256 + threadIdx.x;
    int e = gid >> 4;   // CSR slot; 16 lanes per edge
    int l = gid & 15;
    if (e >= EAUG) return;
    int r = csr_s[e];
    int c = csr_c[e];   // consecutive slots share c -> xgb[c] row stays cache-hot
    const uint4* xr4 = (const uint4*)(xgb + (size_t)r * HD);
    const uint4* xc4 = (const uint4*)(xgb + (size_t)c * HD);
    uint4 ur = xr4[l], uc = xc4[l];
    float d, ss = 0.f;
    d = b2f_lo(ur.x) - b2f_lo(uc.x); ss += d * d;
    d = b2f_hi(ur.x) - b2f_hi(uc.x); ss += d * d;
    d = b2f_lo(ur.y) - b2f_lo(uc.y); ss += d * d;
    d = b2f_hi(ur.y) - b2f_hi(uc.y); ss += d * d;
    d = b2f_lo(ur.z) - b2f_lo(uc.z); ss += d * d;
    d = b2f_hi(ur.z) - b2f_hi(uc.z); ss += d * d;
    d = b2f_lo(ur.w) - b2f_lo(uc.w); ss += d * d;
    d = b2f_hi(ur.w) - b2f_hi(uc.w); ss += d * d;
#pragma unroll
    for (int ofs = 1; ofs < 16; ofs <<= 1) ss += __shfl_xor(ss, ofs);
    if (l == 0) {
        float g = sqrtf(ss + 1e-12f);
        float hh = softplusf(ar[r] + ac[c] + bh[0]);
        float tt = g + hh;                       // >= 0
        float s = 1.f / (1.f + expf(tt));        // sigmoid(-t), in (0, 0.5]
        float ec = expf(s);
        float ed = expf(1.f - s);
        econ[e] = ec;                            // sequential (CSR order)
        edis[e] = ed;
        atomicAdd(&zcon[r], ec);
        atomicAdd(&zdis[r], ed);
    }
}

// ---------------------------------------------------------------- normalize (edge-parallel): wpair[e] = {econ/zcon[r], edis/zdis[r]}
// 64 edges per wave -> divisions amortized 64x vs in-agg_gate computation.
__global__ __launch_bounds__(256) void normalize_w(const int* __restrict__ csr_s,
                                                   const float* __restrict__ econ,
                                                   const float* __restrict__ edis,
                                                   const float* __restrict__ zcon,
                                                   const float* __restrict__ zdis,
                                                   float2* __restrict__ wpair) {
    int e = blockIdx.x * 256 + threadIdx.x;
    if (e >= EAUG) return;
    int r = csr_s[e];
    float2 w;
    w.x = econ[e] / zcon[r];
    w.y = edis[e] / zdis[r];
    wpair[e] = w;
}

// ---------------------------------------------------------------- aggregation + gating (+optional residual)
// weights precomputed (wpair); xcon/xdis gathered as bf16
__global__ __launch_bounds__(256) void agg_gate(const unsigned short* __restrict__ xcon,
                                                const unsigned short* __restrict__ xdis,
                                                const float* __restrict__ xself,
                                                const float2* __restrict__ wpair,
                                                const int* __restrict__ coff,
                                                const int* __restrict__ csr_s,
                                                const float* __restrict__ Wgate,
                                                const float* __restrict__ bgate,
                                                const float* __restrict__ resid,
                                                float* __restrict__ out) {
    int v = (blockIdx.x * 256 + threadIdx.x) >> 6;
    int l = threadIdx.x & 63;
    if (v >= NN) return;
    int beg = coff[v], end = coff[v + 1];
    float cx = 0.f, cy = 0.f, dxv = 0.f, dyv = 0.f;
    for (int j = beg; j < end; j++) {
        int r = csr_s[j];
        float2 w = wpair[j];
        unsigned int ua = ((const unsigned int*)(xcon + (size_t)r * HD))[l];
        unsigned int ub = ((const unsigned int*)(xdis + (size_t)r * HD))[l];
        cx += w.x * b2f_lo(ua); cy += w.x * b2f_hi(ua);
        dxv += w.y * b2f_lo(ub); dyv += w.y * b2f_hi(ub);
    }
    float2 sf = ((const float2*)(xself + (size_t)v * HD))[l];
    float p[3];
#pragma unroll
    for (int i = 0; i < 3; i++) {
        float2 wa = ((const float2*)(Wgate + i * 384))[l];
        float2 wb = ((const float2*)(Wgate + i * 384 + 128))[l];
        float2 wc2 = ((const float2*)(Wgate + i * 384 + 256))[l];
        p[i] = wa.x * cx + wa.y * cy + wb.x * dxv + wb.y * dyv + wc2.x * sf.x + wc2.y * sf.y;
    }
#pragma unroll
    for (int ofs = 1; ofs < 64; ofs <<= 1) {
        p[0] += __shfl_xor(p[0], ofs);
        p[1] += __shfl_xor(p[1], ofs);
        p[2] += __shfl_xor(p[2], ofs);
    }
    float l0 = p[0] + bgate[0], l1 = p[1] + bgate[1], l2 = p[2] + bgate[2];
    float mx = fmaxf(l0, fmaxf(l1, l2));
    float e0 = expf(l0 - mx), e1 = expf(l1 - mx), e2 = expf(l2 - mx);
    float inv = 1.f / (e0 + e1 + e2);
    float g0 = e0 * inv, g1 = e1 * inv, g2 = e2 * inv;
    float2 o;
    o.x = g0 * cx + g1 * dxv + g2 * sf.x;
    o.y = g0 * cy + g1 * dyv + g2 * sf.y;
    if (resid) {
        float2 rv = ((const float2*)(resid + (size_t)v * HD))[l];
        o.x += rv.x; o.y += rv.y;
    }
    ((float2*)(out + (size_t)v * HD))[l] = o;
}

// ---------------------------------------------------------------- classifier via MFMA: out[N,40] = X @ W^T + b
// 64 rows/block; W [40][128] staged bf16, padded to 48 rows (3 col-tiles of 16).
__global__ __launch_bounds__(256) void cls_mfma(const float* __restrict__ X,
                                                const float* __restrict__ W,
                                                const float* __restrict__ b,
                                                float* __restrict__ out) {
    __shared__ __align__(16) unsigned short As[64 * LDA];
    __shared__ __align__(16) unsigned short Wsm[48 * LDA];
    const int t = threadIdx.x;
    const int r0 = blockIdx.x * 64;

    // zero the pad rows 40..47
    for (int i = t; i < 8 * LDA; i += 256) Wsm[40 * LDA + i] = 0;

    {   // stage X rows (fp32 -> bf16)
        const float4* A4 = (const float4*)X;
#pragma unroll
        for (int i = 0; i < 8; i++) {
            int f4 = t + i * 256;
            int row = f4 >> 5, q = f4 & 31;
            float4 v = make_float4(0.f, 0.f, 0.f, 0.f);
            if (r0 + row < NN) v = A4[(size_t)(r0 + row) * 32 + q];
            ushort4 bb;
            bb.x = f2bf(v.x); bb.y = f2bf(v.y); bb.z = f2bf(v.z); bb.w = f2bf(v.w);
            *(ushort4*)&As[row * LDA + q * 4] = bb;
        }
    }
    {   // stage W [40][128]: 1280 float4s = 5 iters exactly
        const float4* W4 = (const float4*)W;
#pragma unroll
        for (int i = 0; i < 5; i++) {
            int f4 = t + i * 256;          // 0..1279
            int c = f4 >> 5, q = f4 & 31;  // c: 0..39
            float4 v = W4[f4];
            ushort4 bb;
            bb.x = f2bf(v.x); bb.y = f2bf(v.y); bb.z = f2bf(v.z); bb.w = f2bf(v.w);
            *(ushort4*)&Wsm[c * LDA + q * 4] = bb;
        }
    }
    __syncthreads();

    const int wv = t >> 6;
    const int ln = t & 63;
    const int lrow = ln & 15;
    const int lk = ln >> 4;

    f32x4 acc[3];
#pragma unroll
    for (int nt = 0; nt < 3; nt++) acc[nt] = (f32x4){0.f, 0.f, 0.f, 0.f};

#pragma unroll
    for (int ks = 0; ks < 4; ks++) {
        int kb = ks * 32 + lk * 8;
        bf16x8 af = *(const bf16x8*)&As[(wv * 16 + lrow) * LDA + kb];
#pragma unroll
        for (int nt = 0; nt < 3; nt++) {
            bf16x8 bfr = *(const bf16x8*)&Wsm[(nt * 16 + lrow) * LDA + kb];
            acc[nt] = __builtin_amdgcn_mfma_f32_16x16x32_bf16(af, bfr, acc[nt], 0, 0, 0);
        }
    }

#pragma unroll
    for (int nt = 0; nt < 3; nt++) {
        int col = nt * 16 + lrow;
        if (col < NC) {
            float bv = b[col];
#pragma unroll
            for (int j = 0; j < 4; j++) {
                int row = r0 + wv * 16 + lk * 4 + j;
                if (row < NN) out[(size_t)row * NC + col] = acc[nt][j] + bv;
            }
        }
    }
}

// ---------------------------------------------------------------- launcher
extern "C" void kernel_launch(void* const* d_in, const int* in_sizes, int n_in,
                              void* d_out, int out_size, void* d_ws, size_t ws_size,
                              hipStream_t stream) {
    const float* x = (const float*)d_in[0];
    const int* ei = (const int*)d_in[1];
    const float* mlp_W = (const float*)d_in[2];
    const float* mlp_b = (const float*)d_in[3];
    const float* mlp_gamma = (const float*)d_in[4];
    const float* mlp_beta = (const float*)d_in[5];
    const float* bn0_gamma = (const float*)d_in[6];
    const float* bn0_beta = (const float*)d_in[7];
    const float* cls_W = (const float*)d_in[8];
    const float* cls_b = (const float*)d_in[9];

    const size_t NF = (size_t)NN * HD;
    float* ws = (float*)d_ws;
    float* raw = ws;                               // fp32 conv raw / x2
    float* h0 = ws + NF;
    float* x1 = ws + 2 * NF;
    unsigned short* xgb = (unsigned short*)(ws + 3 * NF);    // bf16 [NN][128]
    unsigned short* xconb = (unsigned short*)(ws + 4 * NF);  // bf16
    unsigned short* xdisb = (unsigned short*)(ws + 5 * NF);  // bf16
    float* xself = ws + 6 * NF;                    // fp32
    float* ar = ws + 7 * NF;
    float* ac = ar + NN;
    float* econ = ac + NN;
    float* edis = econ + EAUG;
    float* zcon = edis + EAUG;
    float* zdis = zcon + NN;
    float* bnsums = zdis + NN;             // 256
    int* cnt = (int*)(bnsums + 256);       // NN
    int* coff = cnt + NN;                  // NN+1 (padded to NN+2 for alignment)
    int* wp = coff + NN + 2;               // NN
    int* csr_s = wp + NN;                  // EAUG
    int* csr_c = csr_s + EAUG;             // EAUG
    float2* wpair = (float2*)(csr_c + EAUG);  // EAUG float2 (8B-aligned by construction)

    const int EB = (EAUG + 255) / 256;     // 3321
    const int GB = (NN + 63) / 64;         // 782
    const int WB = NN / 4;                 // 12500
    const int EDGEB = EAUG * 16 / 256;     // 53125

    // ---- CSR by col
    hipMemsetAsync(cnt, 0, NN * sizeof(int), stream);
    hist_kernel<<<EB, 256, 0, stream>>>(ei, cnt);
    scan_kernel<<<1, 1024, 0, stream>>>(cnt, coff, wp);
    scatter_kernel<<<EB, 256, 0, stream>>>(ei, wp, csr_s, csr_c);

    // ---- input MLP + BN + relu (all fp32 out)
    gemm_mfma<1, 0><<<GB, 256, 0, stream>>>(x, NN, mlp_W, mlp_b, raw,
                                            nullptr, nullptr, nullptr,
                                            nullptr, nullptr, nullptr,
                                            nullptr, nullptr, nullptr);
    hipMemsetAsync(bnsums, 0, 256 * sizeof(float), stream);
    bn_reduce<<<256, 256, 0, stream>>>(raw, bnsums);
    bn_apply<<<(int)(NF / 4 / 256), 256, 0, stream>>>(raw, bnsums, mlp_gamma, mlp_beta,
                                                      nullptr, h0);

    for (int layer = 0; layer < 2; layer++) {
        const float* Wg = (const float*)d_in[10 + layer * 9 + 0];
        const float* Wh = (const float*)d_in[10 + layer * 9 + 1];
        const float* bh = (const float*)d_in[10 + layer * 9 + 2];
        const float* Wcon = (const float*)d_in[10 + layer * 9 + 3];
        const float* Wdis = (const float*)d_in[10 + layer * 9 + 4];
        const float* Wself = (const float*)d_in[10 + layer * 9 + 5];
        const float* bself = (const float*)d_in[10 + layer * 9 + 6];
        const float* Wgate = (const float*)d_in[10 + layer * 9 + 7];
        const float* bgate = (const float*)d_in[10 + layer * 9 + 8];
        const float* hin = (layer == 0) ? h0 : x1;

        // xg/xcon/xdis stored bf16 (gathered downstream); xself fp32
        gemm_mfma<4, 0b0111><<<GB, 256, 0, stream>>>(hin, NN,
                                                     Wg, nullptr, xgb,
                                                     Wcon, nullptr, xconb,
                                                     Wdis, nullptr, xdisb,
                                                     Wself, bself, xself);
        node_dots<<<WB, 256, 0, stream>>>(xgb, Wh, ar, ac);
        hipMemsetAsync(zcon, 0, NN * sizeof(float), stream);
        hipMemsetAsync(zdis, 0, NN * sizeof(float), stream);
        edge_pass<<<EDGEB, 256, 0, stream>>>(xgb, ar, ac, csr_s, csr_c, bh,
                                             econ, edis, zcon, zdis);
        normalize_w<<<EB, 256, 0, stream>>>(csr_s, econ, edis, zcon, zdis, wpair);
        if (layer == 0) {
            agg_gate<<<WB, 256, 0, stream>>>(xconb, xdisb, xself, wpair,
                                             coff, csr_s, Wgate, bgate, nullptr, raw);
            hipMemsetAsync(bnsums, 0, 256 * sizeof(float), stream);
            bn_reduce<<<256, 256, 0, stream>>>(raw, bnsums);
            bn_apply<<<(int)(NF / 4 / 256), 256, 0, stream>>>(raw, bnsums, bn0_gamma,
                                                              bn0_beta, h0, x1);
        } else {
            agg_gate<<<WB, 256, 0, stream>>>(xconb, xdisb, xself, wpair,
                                             coff, csr_s, Wgate, bgate, x1, raw);
        }
    }

    // ---- classifier (MFMA)
    cls_mfma<<<GB, 256, 0, stream>>>(raw, cls_W, cls_b, (float*)d_out);
}

// Round 16
// 922.061 us; speedup vs baseline: 1.0840x; 1.0840x over previous
//
#include <hip/hip_runtime.h>
#include <math.h>

#define NN 50000
#define NE 800000
#define EAUG (NE + NN)
#define HD 128
#define NC 40
#define BN_EPS 1e-5f
#define LDA 136  // padded LDS stride (elems): 272B/row -> 2-way bank aliasing (free)

typedef short bf16x8 __attribute__((ext_vector_type(8)));
typedef float f32x4 __attribute__((ext_vector_type(4)));

// ---------------------------------------------------------------- utilities
static __device__ __forceinline__ float softplusf(float z) {
    if (z > 20.f) return z;
    if (z < -20.f) return expf(z);
    return log1pf(expf(z));
}

static __device__ __forceinline__ unsigned short f2bf(float f) {
    union { float f; unsigned int u; } v;
    v.f = f;
    unsigned int u = v.u;
    unsigned int r = (u + 0x7fffu + ((u >> 16) & 1u)) >> 16;
    return (unsigned short)r;
}
static __device__ __forceinline__ float b2f_lo(unsigned int u) {
    union { unsigned int i; float f; } v; v.i = u << 16; return v.f;
}
static __device__ __forceinline__ float b2f_hi(unsigned int u) {
    union { unsigned int i; float f; } v; v.i = u & 0xffff0000u; return v.f;
}

// ---------------------------------------------------------------- CSR build
__global__ __launch_bounds__(256) void hist_kernel(const int* __restrict__ ei,
                                                   int* __restrict__ cnt) {
    int e = blockIdx.x * 256 + threadIdx.x;
    if (e >= EAUG) return;
    int c = (e < NE) ? ei[NE + e] : (e - NE);
    atomicAdd(&cnt[c], 1);
}

__global__ __launch_bounds__(1024) void scan_kernel(const int* __restrict__ cnt,
                                                    int* __restrict__ off,
                                                    int* __restrict__ wp) {
    __shared__ int sdata[1024];
    __shared__ int carry;
    int tid = threadIdx.x;
    if (tid == 0) carry = 0;
    __syncthreads();
    for (int base = 0; base < NN; base += 1024) {
        int i = base + tid;
        int v = (i < NN) ? cnt[i] : 0;
        sdata[tid] = v;
        __syncthreads();
        for (int ofs = 1; ofs < 1024; ofs <<= 1) {
            int t = (tid >= ofs) ? sdata[tid - ofs] : 0;
            __syncthreads();
            sdata[tid] += t;
            __syncthreads();
        }
        int excl = sdata[tid] - v + carry;
        if (i < NN) { off[i] = excl; wp[i] = excl; }
        __syncthreads();
        if (tid == 1023) carry += sdata[1023];
        __syncthreads();
    }
    if (tid == 0) off[NN] = carry;   // == EAUG
}

// stores (src,dst) per CSR slot; no edge-id indirection needed downstream
__global__ __launch_bounds__(256) void scatter_kernel(const int* __restrict__ ei,
                                                      int* __restrict__ wp,
                                                      int* __restrict__ csr_s,
                                                      int* __restrict__ csr_c) {
    int e = blockIdx.x * 256 + threadIdx.x;
    if (e >= EAUG) return;
    int r, c;
    if (e < NE) { r = ei[e]; c = ei[NE + e]; } else { r = c = e - NE; }
    int pos = atomicAdd(&wp[c], 1);
    csr_s[pos] = r;
    csr_c[pos] = c;
}

// ---------------------------------------------------------------- MFMA GEMM: O_m = A @ W_m^T (+bias)
// BFMASK bit m: output m stored as bf16 (ushort), else fp32.
template <int NM, int BFMASK>
__global__ __launch_bounds__(256) void gemm_mfma(
    const float* __restrict__ A, int nrows,
    const float* __restrict__ W0, const float* __restrict__ B0, void* __restrict__ O0,
    const float* __restrict__ W1, const float* __restrict__ B1, void* __restrict__ O1,
    const float* __restrict__ W2, const float* __restrict__ B2, void* __restrict__ O2,
    const float* __restrict__ W3, const float* __restrict__ B3, void* __restrict__ O3) {
    __shared__ __align__(16) unsigned short As[64 * LDA];
    __shared__ __align__(16) unsigned short Bs_lds[128 * LDA];
    const int t = threadIdx.x;
    const int r0 = blockIdx.x * 64;

    {   // stage A tile (fp32 -> bf16)
        const float4* A4 = (const float4*)A;
#pragma unroll
        for (int i = 0; i < 8; i++) {
            int f4 = t + i * 256;
            int row = f4 >> 5, q = f4 & 31;
            float4 v = make_float4(0.f, 0.f, 0.f, 0.f);
            if (r0 + row < nrows) v = A4[(size_t)(r0 + row) * 32 + q];
            ushort4 b;
            b.x = f2bf(v.x); b.y = f2bf(v.y); b.z = f2bf(v.z); b.w = f2bf(v.w);
            *(ushort4*)&As[row * LDA + q * 4] = b;
        }
    }

    const float* Ws[4] = {W0, W1, W2, W3};
    const float* Bb[4] = {B0, B1, B2, B3};
    void* Os[4] = {O0, O1, O2, O3};
    const int wv = t >> 6;
    const int ln = t & 63;
    const int lrow = ln & 15;
    const int lk = ln >> 4;

#pragma unroll
    for (int m = 0; m < NM; m++) {
        __syncthreads();
        {
            const float4* Wm4 = (const float4*)Ws[m];
#pragma unroll
            for (int i = 0; i < 16; i++) {
                int f4 = t + i * 256;
                int c = f4 >> 5, q = f4 & 31;
                float4 v = Wm4[f4];
                ushort4 b;
                b.x = f2bf(v.x); b.y = f2bf(v.y); b.z = f2bf(v.z); b.w = f2bf(v.w);
                *(ushort4*)&Bs_lds[c * LDA + q * 4] = b;
            }
        }
        __syncthreads();

        f32x4 acc[8];
#pragma unroll
        for (int nt = 0; nt < 8; nt++) acc[nt] = (f32x4){0.f, 0.f, 0.f, 0.f};

#pragma unroll
        for (int ks = 0; ks < 4; ks++) {
            int kb = ks * 32 + lk * 8;
            bf16x8 af = *(const bf16x8*)&As[(wv * 16 + lrow) * LDA + kb];
#pragma unroll
            for (int nt = 0; nt < 8; nt++) {
                bf16x8 bfr = *(const bf16x8*)&Bs_lds[(nt * 16 + lrow) * LDA + kb];
                acc[nt] = __builtin_amdgcn_mfma_f32_16x16x32_bf16(af, bfr, acc[nt], 0, 0, 0);
            }
        }

        const float* bias = Bb[m];
#pragma unroll
        for (int nt = 0; nt < 8; nt++) {
            int col = nt * 16 + lrow;
            float bv = bias ? bias[col] : 0.f;
#pragma unroll
            for (int j = 0; j < 4; j++) {
                int row = r0 + wv * 16 + lk * 4 + j;
                if (row < nrows) {
                    float val = acc[nt][j] + bv;
                    if ((BFMASK >> m) & 1)
                        ((unsigned short*)Os[m])[(size_t)row * HD + col] = f2bf(val);
                    else
                        ((float*)Os[m])[(size_t)row * HD + col] = val;
                }
            }
        }
    }
}

// ---------------------------------------------------------------- batchnorm
__global__ __launch_bounds__(256) void bn_reduce(const float* __restrict__ X,
                                                 float* __restrict__ sums) {
    int f = threadIdx.x & 127;
    int half = threadIdx.x >> 7;
    float s1 = 0.f, s2 = 0.f;
    for (int r = blockIdx.x * 2 + half; r < NN; r += gridDim.x * 2) {
        float v = X[(size_t)r * HD + f];
        s1 += v;
        s2 += v * v;
    }
    __shared__ float sm[512];
    sm[threadIdx.x] = s1;
    sm[256 + threadIdx.x] = s2;
    __syncthreads();
    if (half == 0) {
        atomicAdd(&sums[f], sm[f] + sm[128 + f]);
        atomicAdd(&sums[128 + f], sm[256 + f] + sm[256 + 128 + f]);
    }
}

__global__ __launch_bounds__(256) void bn_apply(const float* __restrict__ in,
                                                const float* __restrict__ sums,
                                                const float* __restrict__ gamma,
                                                const float* __restrict__ beta,
                                                const float* __restrict__ resid,
                                                float* __restrict__ out) {
    int idx = blockIdx.x * 256 + threadIdx.x;
    int f4 = idx & 31;
    float4 s1 = ((const float4*)sums)[f4];
    float4 s2 = ((const float4*)sums)[32 + f4];
    float4 g = ((const float4*)gamma)[f4];
    float4 bt = ((const float4*)beta)[f4];
    float4 v = ((const float4*)in)[idx];
    const float invn = 1.f / (float)NN;
    float4 o;
#define BN1(comp)                                                          \
    {                                                                      \
        float mean = s1.comp * invn;                                       \
        float var = s2.comp * invn - mean * mean;                          \
        float y = g.comp * (v.comp - mean) * rsqrtf(var + BN_EPS) + bt.comp; \
        o.comp = fmaxf(y, 0.f);                                            \
    }
    BN1(x) BN1(y) BN1(z) BN1(w)
#undef BN1
    if (resid) {
        float4 rv = ((const float4*)resid)[idx];
        o.x += rv.x; o.y += rv.y; o.z += rv.z; o.w += rv.w;
    }
    ((float4*)out)[idx] = o;
}

// ---------------------------------------------------------------- per-node dots from bf16 xg
__global__ __launch_bounds__(256) void node_dots(const unsigned short* __restrict__ xgb,
                                                 const float* __restrict__ Wh,
                                                 float* __restrict__ ar,
                                                 float* __restrict__ ac) {
    int wid = (blockIdx.x * 256 + threadIdx.x) >> 6;
    int l = threadIdx.x & 63;
    if (wid >= NN) return;
    unsigned int u = ((const unsigned int*)(xgb + (size_t)wid * HD))[l];
    float fx = b2f_lo(u), fy = b2f_hi(u);
    float2 wa = ((const float2*)Wh)[l];
    float2 wb = ((const float2*)Wh)[64 + l];
    float pa = fx * wa.x + fy * wa.y;
    float pb = fx * wb.x + fy * wb.y;
#pragma unroll
    for (int ofs = 1; ofs < 64; ofs <<= 1) {
        pa += __shfl_xor(pa, ofs);
        pb += __shfl_xor(pb, ofs);
    }
    if (l == 0) { ar[wid] = pa; ac[wid] = pb; }
}

// ---------------------------------------------------------------- edge pass (CSR order): s_ij -> exp terms + z sums
__global__ __launch_bounds__(256) void edge_pass(const unsigned short* __restrict__ xgb,
                                                 const float* __restrict__ ar,
                                                 const float* __restrict__ ac,
                                                 const int* __restrict__ csr_s,
                                                 const int* __restrict__ csr_c,
                                                 const float* __restrict__ bh,
                                                 float* __restrict__ econ,
                                                 float* __restrict__ edis,
                                                 float* __restrict__ zcon,
                                                 float* __restrict__ zdis) {
    int gid = blockIdx.x * 256 + threadIdx.x;
    int e = gid >> 4;   // CSR slot; 16 lanes per edge
    int l = gid & 15;
    if (e >= EAUG) return;
    int r = csr_s[e];
    int c = csr_c[e];   // consecutive slots share c -> xgb[c] row stays cache-hot
    const uint4* xr4 = (const uint4*)(xgb + (size_t)r * HD);
    const uint4* xc4 = (const uint4*)(xgb + (size_t)c * HD);
    uint4 ur = xr4[l], uc = xc4[l];
    float d, ss = 0.f;
    d = b2f_lo(ur.x) - b2f_lo(uc.x); ss += d * d;
    d = b2f_hi(ur.x) - b2f_hi(uc.x); ss += d * d;
    d = b2f_lo(ur.y) - b2f_lo(uc.y); ss += d * d;
    d = b2f_hi(ur.y) - b2f_hi(uc.y); ss += d * d;
    d = b2f_lo(ur.z) - b2f_lo(uc.z); ss += d * d;
    d = b2f_hi(ur.z) - b2f_hi(uc.z); ss += d * d;
    d = b2f_lo(ur.w) - b2f_lo(uc.w); ss += d * d;
    d = b2f_hi(ur.w) - b2f_hi(uc.w); ss += d * d;
#pragma unroll
    for (int ofs = 1; ofs < 16; ofs <<= 1) ss += __shfl_xor(ss, ofs);
    if (l == 0) {
        float g = sqrtf(ss + 1e-12f);
        float hh = softplusf(ar[r] + ac[c] + bh[0]);
        float tt = g + hh;                       // >= 0
        float s = 1.f / (1.f + expf(tt));        // sigmoid(-t), in (0, 0.5]
        float ec = expf(s);
        float ed = expf(1.f - s);
        econ[e] = ec;                            // sequential (CSR order)
        edis[e] = ed;
        atomicAdd(&zcon[r], ec);
        atomicAdd(&zdis[r], ed);
    }
}

// ---------------------------------------------------------------- normalize (edge-parallel): wpair[e] = {econ/zcon[r], edis/zdis[r]}
__global__ __launch_bounds__(256) void normalize_w(const int* __restrict__ csr_s,
                                                   const float* __restrict__ econ,
                                                   const float* __restrict__ edis,
                                                   const float* __restrict__ zcon,
                                                   const float* __restrict__ zdis,
                                                   float2* __restrict__ wpair) {
    int e = blockIdx.x * 256 + threadIdx.x;
    if (e >= EAUG) return;
    int r = csr_s[e];
    float2 w;
    w.x = econ[e] / zcon[r];
    w.y = edis[e] / zdis[r];
    wpair[e] = w;
}

// ---------------------------------------------------------------- aggregation + gating (+optional residual)
// weights precomputed (wpair); xcon/xdis gathered as bf16.
// Edge loop manually unrolled x4 with grouped gathers: 8 outstanding random
// loads per wave instead of 2 -> hides L2-miss latency (VGPR 20 showed the
// compiler wasn't unrolling). FMAs applied in index order (bitwise-identical).
__global__ __launch_bounds__(256) void agg_gate(const unsigned short* __restrict__ xcon,
                                                const unsigned short* __restrict__ xdis,
                                                const float* __restrict__ xself,
                                                const float2* __restrict__ wpair,
                                                const int* __restrict__ coff,
                                                const int* __restrict__ csr_s,
                                                const float* __restrict__ Wgate,
                                                const float* __restrict__ bgate,
                                                const float* __restrict__ resid,
                                                float* __restrict__ out) {
    int v = (blockIdx.x * 256 + threadIdx.x) >> 6;
    int l = threadIdx.x & 63;
    if (v >= NN) return;
    int beg = coff[v], end = coff[v + 1];
    float cx = 0.f, cy = 0.f, dxv = 0.f, dyv = 0.f;
    int j = beg;
    for (; j + 3 < end; j += 4) {
        int r0 = csr_s[j], r1 = csr_s[j + 1], r2 = csr_s[j + 2], r3 = csr_s[j + 3];
        float2 w0 = wpair[j], w1 = wpair[j + 1], w2 = wpair[j + 2], w3 = wpair[j + 3];
        unsigned int ua0 = ((const unsigned int*)(xcon + (size_t)r0 * HD))[l];
        unsigned int ub0 = ((const unsigned int*)(xdis + (size_t)r0 * HD))[l];
        unsigned int ua1 = ((const unsigned int*)(xcon + (size_t)r1 * HD))[l];
        unsigned int ub1 = ((const unsigned int*)(xdis + (size_t)r1 * HD))[l];
        unsigned int ua2 = ((const unsigned int*)(xcon + (size_t)r2 * HD))[l];
        unsigned int ub2 = ((const unsigned int*)(xdis + (size_t)r2 * HD))[l];
        unsigned int ua3 = ((const unsigned int*)(xcon + (size_t)r3 * HD))[l];
        unsigned int ub3 = ((const unsigned int*)(xdis + (size_t)r3 * HD))[l];
        cx += w0.x * b2f_lo(ua0); cy += w0.x * b2f_hi(ua0);
        dxv += w0.y * b2f_lo(ub0); dyv += w0.y * b2f_hi(ub0);
        cx += w1.x * b2f_lo(ua1); cy += w1.x * b2f_hi(ua1);
        dxv += w1.y * b2f_lo(ub1); dyv += w1.y * b2f_hi(ub1);
        cx += w2.x * b2f_lo(ua2); cy += w2.x * b2f_hi(ua2);
        dxv += w2.y * b2f_lo(ub2); dyv += w2.y * b2f_hi(ub2);
        cx += w3.x * b2f_lo(ua3); cy += w3.x * b2f_hi(ua3);
        dxv += w3.y * b2f_lo(ub3); dyv += w3.y * b2f_hi(ub3);
    }
    for (; j < end; j++) {
        int r = csr_s[j];
        float2 w = wpair[j];
        unsigned int ua = ((const unsigned int*)(xcon + (size_t)r * HD))[l];
        unsigned int ub = ((const unsigned int*)(xdis + (size_t)r * HD))[l];
        cx += w.x * b2f_lo(ua); cy += w.x * b2f_hi(ua);
        dxv += w.y * b2f_lo(ub); dyv += w.y * b2f_hi(ub);
    }
    float2 sf = ((const float2*)(xself + (size_t)v * HD))[l];
    float p[3];
#pragma unroll
    for (int i = 0; i < 3; i++) {
        float2 wa = ((const float2*)(Wgate + i * 384))[l];
        float2 wb = ((const float2*)(Wgate + i * 384 + 128))[l];
        float2 wc2 = ((const float2*)(Wgate + i * 384 + 256))[l];
        p[i] = wa.x * cx + wa.y * cy + wb.x * dxv + wb.y * dyv + wc2.x * sf.x + wc2.y * sf.y;
    }
#pragma unroll
    for (int ofs = 1; ofs < 64; ofs <<= 1) {
        p[0] += __shfl_xor(p[0], ofs);
        p[1] += __shfl_xor(p[1], ofs);
        p[2] += __shfl_xor(p[2], ofs);
    }
    float l0 = p[0] + bgate[0], l1 = p[1] + bgate[1], l2 = p[2] + bgate[2];
    float mx = fmaxf(l0, fmaxf(l1, l2));
    float e0 = expf(l0 - mx), e1 = expf(l1 - mx), e2 = expf(l2 - mx);
    float inv = 1.f / (e0 + e1 + e2);
    float g0 = e0 * inv, g1 = e1 * inv, g2 = e2 * inv;
    float2 o;
    o.x = g0 * cx + g1 * dxv + g2 * sf.x;
    o.y = g0 * cy + g1 * dyv + g2 * sf.y;
    if (resid) {
        float2 rv = ((const float2*)(resid + (size_t)v * HD))[l];
        o.x += rv.x; o.y += rv.y;
    }
    ((float2*)(out + (size_t)v * HD))[l] = o;
}

// ---------------------------------------------------------------- classifier via MFMA: out[N,40] = X @ W^T + b
// 64 rows/block; W [40][128] staged bf16, padded to 48 rows (3 col-tiles of 16).
__global__ __launch_bounds__(256) void cls_mfma(const float* __restrict__ X,
                                                const float* __restrict__ W,
                                                const float* __restrict__ b,
                                                float* __restrict__ out) {
    __shared__ __align__(16) unsigned short As[64 * LDA];
    __shared__ __align__(16) unsigned short Wsm[48 * LDA];
    const int t = threadIdx.x;
    const int r0 = blockIdx.x * 64;

    // zero the pad rows 40..47
    for (int i = t; i < 8 * LDA; i += 256) Wsm[40 * LDA + i] = 0;

    {   // stage X rows (fp32 -> bf16)
        const float4* A4 = (const float4*)X;
#pragma unroll
        for (int i = 0; i < 8; i++) {
            int f4 = t + i * 256;
            int row = f4 >> 5, q = f4 & 31;
            float4 v = make_float4(0.f, 0.f, 0.f, 0.f);
            if (r0 + row < NN) v = A4[(size_t)(r0 + row) * 32 + q];
            ushort4 bb;
            bb.x = f2bf(v.x); bb.y = f2bf(v.y); bb.z = f2bf(v.z); bb.w = f2bf(v.w);
            *(ushort4*)&As[row * LDA + q * 4] = bb;
        }
    }
    {   // stage W [40][128]: 1280 float4s = 5 iters exactly
        const float4* W4 = (const float4*)W;
#pragma unroll
        for (int i = 0; i < 5; i++) {
            int f4 = t + i * 256;          // 0..1279
            int c = f4 >> 5, q = f4 & 31;  // c: 0..39
            float4 v = W4[f4];
            ushort4 bb;
            bb.x = f2bf(v.x); bb.y = f2bf(v.y); bb.z = f2bf(v.z); bb.w = f2bf(v.w);
            *(ushort4*)&Wsm[c * LDA + q * 4] = bb;
        }
    }
    __syncthreads();

    const int wv = t >> 6;
    const int ln = t & 63;
    const int lrow = ln & 15;
    const int lk = ln >> 4;

    f32x4 acc[3];
#pragma unroll
    for (int nt = 0; nt < 3; nt++) acc[nt] = (f32x4){0.f, 0.f, 0.f, 0.f};

#pragma unroll
    for (int ks = 0; ks < 4; ks++) {
        int kb = ks * 32 + lk * 8;
        bf16x8 af = *(const bf16x8*)&As[(wv * 16 + lrow) * LDA + kb];
#pragma unroll
        for (int nt = 0; nt < 3; nt++) {
            bf16x8 bfr = *(const bf16x8*)&Wsm[(nt * 16 + lrow) * LDA + kb];
            acc[nt] = __builtin_amdgcn_mfma_f32_16x16x32_bf16(af, bfr, acc[nt], 0, 0, 0);
        }
    }

#pragma unroll
    for (int nt = 0; nt < 3; nt++) {
        int col = nt * 16 + lrow;
        if (col < NC) {
            float bv = b[col];
#pragma unroll
            for (int j = 0; j < 4; j++) {
                int row = r0 + wv * 16 + lk * 4 + j;
                if (row < NN) out[(size_t)row * NC + col] = acc[nt][j] + bv;
            }
        }
    }
}

// ---------------------------------------------------------------- launcher
extern "C" void kernel_launch(void* const* d_in, const int* in_sizes, int n_in,
                              void* d_out, int out_size, void* d_ws, size_t ws_size,
                              hipStream_t stream) {
    const float* x = (const float*)d_in[0];
    const int* ei = (const int*)d_in[1];
    const float* mlp_W = (const float*)d_in[2];
    const float* mlp_b = (const float*)d_in[3];
    const float* mlp_gamma = (const float*)d_in[4];
    const float* mlp_beta = (const float*)d_in[5];
    const float* bn0_gamma = (const float*)d_in[6];
    const float* bn0_beta = (const float*)d_in[7];
    const float* cls_W = (const float*)d_in[8];
    const float* cls_b = (const float*)d_in[9];

    const size_t NF = (size_t)NN * HD;
    float* ws = (float*)d_ws;
    float* raw = ws;                               // fp32 conv raw / x2
    float* h0 = ws + NF;
    float* x1 = ws + 2 * NF;
    unsigned short* xgb = (unsigned short*)(ws + 3 * NF);    // bf16 [NN][128]
    unsigned short* xconb = (unsigned short*)(ws + 4 * NF);  // bf16
    unsigned short* xdisb = (unsigned short*)(ws + 5 * NF);  // bf16
    float* xself = ws + 6 * NF;                    // fp32
    float* ar = ws + 7 * NF;
    float* ac = ar + NN;
    float* econ = ac + NN;
    float* edis = econ + EAUG;
    float* zcon = edis + EAUG;
    float* zdis = zcon + NN;
    float* bnsums = zdis + NN;             // 256
    int* cnt = (int*)(bnsums + 256);       // NN
    int* coff = cnt + NN;                  // NN+1 (padded to NN+2 for alignment)
    int* wp = coff + NN + 2;               // NN
    int* csr_s = wp + NN;                  // EAUG
    int* csr_c = csr_s + EAUG;             // EAUG
    float2* wpair = (float2*)(csr_c + EAUG);  // EAUG float2 (8B-aligned by construction)

    const int EB = (EAUG + 255) / 256;     // 3321
    const int GB = (NN + 63) / 64;         // 782
    const int WB = NN / 4;                 // 12500
    const int EDGEB = EAUG * 16 / 256;     // 53125

    // ---- CSR by col
    hipMemsetAsync(cnt, 0, NN * sizeof(int), stream);
    hist_kernel<<<EB, 256, 0, stream>>>(ei, cnt);
    scan_kernel<<<1, 1024, 0, stream>>>(cnt, coff, wp);
    scatter_kernel<<<EB, 256, 0, stream>>>(ei, wp, csr_s, csr_c);

    // ---- input MLP + BN + relu (all fp32 out)
    gemm_mfma<1, 0><<<GB, 256, 0, stream>>>(x, NN, mlp_W, mlp_b, raw,
                                            nullptr, nullptr, nullptr,
                                            nullptr, nullptr, nullptr,
                                            nullptr, nullptr, nullptr);
    hipMemsetAsync(bnsums, 0, 256 * sizeof(float), stream);
    bn_reduce<<<256, 256, 0, stream>>>(raw, bnsums);
    bn_apply<<<(int)(NF / 4 / 256), 256, 0, stream>>>(raw, bnsums, mlp_gamma, mlp_beta,
                                                      nullptr, h0);

    for (int layer = 0; layer < 2; layer++) {
        const float* Wg = (const float*)d_in[10 + layer * 9 + 0];
        const float* Wh = (const float*)d_in[10 + layer * 9 + 1];
        const float* bh = (const float*)d_in[10 + layer * 9 + 2];
        const float* Wcon = (const float*)d_in[10 + layer * 9 + 3];
        const float* Wdis = (const float*)d_in[10 + layer * 9 + 4];
        const float* Wself = (const float*)d_in[10 + layer * 9 + 5];
        const float* bself = (const float*)d_in[10 + layer * 9 + 6];
        const float* Wgate = (const float*)d_in[10 + layer * 9 + 7];
        const float* bgate = (const float*)d_in[10 + layer * 9 + 8];
        const float* hin = (layer == 0) ? h0 : x1;

        // xg/xcon/xdis stored bf16 (gathered downstream); xself fp32
        gemm_mfma<4, 0b0111><<<GB, 256, 0, stream>>>(hin, NN,
                                                     Wg, nullptr, xgb,
                                                     Wcon, nullptr, xconb,
                                                     Wdis, nullptr, xdisb,
                                                     Wself, bself, xself);
        node_dots<<<WB, 256, 0, stream>>>(xgb, Wh, ar, ac);
        hipMemsetAsync(zcon, 0, NN * sizeof(float), stream);
        hipMemsetAsync(zdis, 0, NN * sizeof(float), stream);
        edge_pass<<<EDGEB, 256, 0, stream>>>(xgb, ar, ac, csr_s, csr_c, bh,
                                             econ, edis, zcon, zdis);
        normalize_w<<<EB, 256, 0, stream>>>(csr_s, econ, edis, zcon, zdis, wpair);
        if (layer == 0) {
            agg_gate<<<WB, 256, 0, stream>>>(xconb, xdisb, xself, wpair,
                                             coff, csr_s, Wgate, bgate, nullptr, raw);
            hipMemsetAsync(bnsums, 0, 256 * sizeof(float), stream);
            bn_reduce<<<256, 256, 0, stream>>>(raw, bnsums);
            bn_apply<<<(int)(NF / 4 / 256), 256, 0, stream>>>(raw, bnsums, bn0_gamma,
                                                              bn0_beta, h0, x1);
        } else {
            agg_gate<<<WB, 256, 0, stream>>>(xconb, xdisb, xself, wpair,
                                             coff, csr_s, Wgate, bgate, x1, raw);
        }
    }

    // ---- classifier (MFMA)
    cls_mfma<<<GB, 256, 0, stream>>>(raw, cls_W, cls_b, (float*)d_out);
}